// Round 1
// baseline (42.934 us; speedup 1.0000x reference)
//
#include <hip/hip_runtime.h>

// GlassBlur (ImageNet-C style) with sigma=0.05 -> gaussian radius 0 -> identity blur.
// The op is exactly a sequence of 49284 sequential pixel swaps = one permutation.
// Phase 1: per-row segment permutations (222 independent sequential chains, 4-reg window).
// Phase 2: per-pixel chase composing segments, then exact fp32 gather.

static constexpr int IMH = 224;
static constexpr int IMW = 224;
static constexpr int NROW = 222;          // swap rows h = 2..223
static constexpr int TAB_ROW_STRIDE = IMW * 2;  // [w][2] ushorts per segment row

// Cell encoding in table: (row << 8) | col  (row,col < 256). 16 bits.

__global__ __launch_bounds__(256) void glass_build(const int2* __restrict__ dxy,
                                                   unsigned short* __restrict__ table) {
    int t = threadIdx.x;
    if (t >= NROW) return;
    int h = t + 2;                         // this thread simulates swap-row h
    int base = (223 - h) * 222;            // first swap index of this row

    // Sliding 4-cell window: column w (t1=row h-1, b1=row h) and column w-1 (t0,b0).
    unsigned int t1 = ((unsigned)(h - 1) << 8) | 223u;
    unsigned int b1 = ((unsigned)h << 8) | 223u;
    unsigned int t0 = ((unsigned)(h - 1) << 8) | 222u;
    unsigned int b0 = ((unsigned)h << 8) | 222u;

    unsigned short* rowTab = table + (h - 2) * TAB_ROW_STRIDE;

    #pragma unroll 2
    for (int w = 223; w >= 2; --w) {
        int2 d = dxy[base + (223 - w)];    // d.x = dx (col delta), d.y = dy (row delta); in {-1,0}
        unsigned int ob1 = b1;
        // swap (h,w) <-> (h+dy, w+dx)
        unsigned int partner = (d.y < 0) ? ((d.x < 0) ? t0 : t1)
                                         : ((d.x < 0) ? b0 : b1);
        b1 = partner;
        if (d.y < 0) { if (d.x < 0) t0 = ob1; else t1 = ob1; }
        else         { if (d.x < 0) b0 = ob1; /* (0,0): b1 already = ob1 */ }
        // column w is now final for this segment: emit [w][0]=top(h-1), [w][1]=bot(h)
        *reinterpret_cast<unsigned int*>(rowTab + 2 * w) = (b1 << 16) | t1;
        // slide window left
        t1 = t0; b1 = b0;
        t0 = ((unsigned)(h - 1) << 8) | (unsigned)(w - 2);
        b0 = ((unsigned)h << 8) | (unsigned)(w - 2);
    }
    // column 1 (carried), column 0 (never touched -> identity)
    *reinterpret_cast<unsigned int*>(rowTab + 2) = (b1 << 16) | t1;
    *reinterpret_cast<unsigned int*>(rowTab) =
        (((unsigned)h << 8) << 16) | ((unsigned)(h - 1) << 8);
}

__global__ __launch_bounds__(256) void glass_apply(const float* __restrict__ img,
                                                   const unsigned short* __restrict__ table,
                                                   float* __restrict__ out) {
    int p = blockIdx.x * 256 + threadIdx.x;
    if (p >= IMH * IMW) return;
    int r = p / IMW;
    int c = p - r * IMW;
    int qr = r, qc = c;
    if (r >= 1) {
        int h = (r < 2) ? 2 : r;           // first segment whose domain {h-1,h} contains r
        while (h <= 223) {
            unsigned int v = table[(h - 2) * TAB_ROW_STRIDE + qc * 2 + (qr - (h - 1))];
            qr = (int)(v >> 8);
            qc = (int)(v & 255u);
            if (qr != h) break;            // landed in row h-1 -> frozen for all later segments
            ++h;
        }
    }
    int q = qr * IMW + qc;
    float v0 = img[3 * q + 0];
    float v1 = img[3 * q + 1];
    float v2 = img[3 * q + 2];
    // reference clips to [0,1]; inputs are uniform [0,1) so this is identity (kept for fidelity)
    v0 = fminf(fmaxf(v0, 0.0f), 1.0f);
    v1 = fminf(fmaxf(v1, 0.0f), 1.0f);
    v2 = fminf(fmaxf(v2, 0.0f), 1.0f);
    out[3 * p + 0] = v0;
    out[3 * p + 1] = v1;
    out[3 * p + 2] = v2;
}

extern "C" void kernel_launch(void* const* d_in, const int* in_sizes, int n_in,
                              void* d_out, int out_size, void* d_ws, size_t ws_size,
                              hipStream_t stream) {
    const float* img = (const float*)d_in[0];
    const int2* dxy = (const int2*)d_in[1];
    float* out = (float*)d_out;
    unsigned short* table = (unsigned short*)d_ws;   // needs 222*224*2*2 = 198,912 B

    hipLaunchKernelGGL(glass_build, dim3(1), dim3(256), 0, stream, dxy, table);
    hipLaunchKernelGGL(glass_apply, dim3((IMH * IMW + 255) / 256), dim3(256), 0, stream,
                       img, table, out);
}

// Round 2
// 24.378 us; speedup vs baseline: 1.7612x; 1.7612x over previous
//
#include <hip/hip_runtime.h>

// GlassBlur (ImageNet-C) sigma=0.05 -> gaussian radius 0 -> blur is identity.
// Op == 49284 sequential pixel swaps == one permutation. Computed exactly:
// Phase 1 (glass_build): per swap-row h, the 222 swaps compose into a segment
//   permutation over rows {h-1,h}, simulated with a 4-register sliding window.
//   One WAVE per row: 64 lanes coalesce-load the row's dxy (2-bit codes),
//   broadcast via readlane -> wave-uniform scalar chain, coalesced stores at end.
// Phase 2 (glass_apply): per output pixel, chase through segment tables
//   (expected ~2 dependent L2 loads), then exact fp32 gather + clamp.

static constexpr int IMH = 224;
static constexpr int IMW = 224;
static constexpr int NROW = 222;                // swap rows h = 2..223
static constexpr int TAB_ROW_STRIDE = IMW * 2;  // [w][2] ushorts per segment row

// Cell encoding: (row << 8) | col (both < 256).

__global__ __launch_bounds__(64) void glass_build(const int2* __restrict__ dxy,
                                                  unsigned short* __restrict__ table) {
    int row = blockIdx.x;              // 0..221
    int h = row + 2;                   // swap-row simulated by this wave
    int base = (221 - row) * 222;      // first swap index of this row
    int lane = threadIdx.x;            // 0..63

    // Coalesced load of the row's 222 dxy entries -> 2-bit codes per lane.
    // code bit1 = (dy<0), bit0 = (dx<0);  dx,dy in {-1,0}.
    unsigned codes[4] = {0u, 0u, 0u, 0u};
    {
        int2 d;
        d = dxy[base + lane];        codes[0] = ((d.y < 0) ? 2u : 0u) | ((d.x < 0) ? 1u : 0u);
        d = dxy[base + lane + 64];   codes[1] = ((d.y < 0) ? 2u : 0u) | ((d.x < 0) ? 1u : 0u);
        d = dxy[base + lane + 128];  codes[2] = ((d.y < 0) ? 2u : 0u) | ((d.x < 0) ? 1u : 0u);
        if (lane + 192 < 222) {      // guard: row has only 222 entries
            d = dxy[base + lane + 192];
            codes[3] = ((d.y < 0) ? 2u : 0u) | ((d.x < 0) ? 1u : 0u);
        }
    }

    // Sliding 4-cell window: column w (t1=row h-1, b1=row h), column w-1 (t0,b0).
    unsigned t1 = ((unsigned)(h - 1) << 8) | 223u;
    unsigned b1 = ((unsigned)h << 8) | 223u;
    unsigned t0 = ((unsigned)(h - 1) << 8) | 222u;
    unsigned b0 = ((unsigned)h << 8) | 222u;

    unsigned v0 = 0, v1 = 0, v2 = 0, v3 = 0;   // lane (i&63) keeps entry for iter i

    #pragma unroll
    for (int i = 0; i < 222; ++i) {            // iteration i handles column w = 223-i
        unsigned code = (unsigned)__builtin_amdgcn_readlane((int)codes[i >> 6], i & 63);
        bool dy = (code & 2u) != 0u;
        bool dx = (code & 1u) != 0u;
        unsigned ob1 = b1;
        // swap (h,w) <-> (h+dyv, w+dxv)
        unsigned partner = dy ? (dx ? t0 : t1) : (dx ? b0 : b1);
        b1 = partner;
        t0 = (dy && dx) ? ob1 : t0;
        t1 = (dy && !dx) ? ob1 : t1;
        b0 = (!dy && dx) ? ob1 : b0;
        // column w = 223-i is final for this segment: entry [w] = (bot<<16)|top
        unsigned val = (b1 << 16) | t1;
        if ((i & 63) == lane) {
            switch (i >> 6) {                  // i is a literal -> static reg select
                case 0: v0 = val; break;
                case 1: v1 = val; break;
                case 2: v2 = val; break;
                default: v3 = val; break;
            }
        }
        // slide window left
        t1 = t0; b1 = b0;
        unsigned wn = (unsigned)(221 - i);     // = w-2
        t0 = ((unsigned)(h - 1) << 8) | wn;
        b0 = ((unsigned)h << 8) | wn;
    }

    unsigned* rowTab32 = reinterpret_cast<unsigned*>(table + row * TAB_ROW_STRIDE);
    // iter i -> w = 223-i; chunk k stored by lane i-64k at column (223-64k)-lane
    rowTab32[223 - lane] = v0;
    rowTab32[159 - lane] = v1;
    rowTab32[95 - lane]  = v2;
    if (lane < 30) rowTab32[31 - lane] = v3;   // i = 192..221 -> w = 31..2
    if (lane == 0) {
        rowTab32[1] = (b1 << 16) | t1;         // column 1 (carried window)
        rowTab32[0] = (((unsigned)h << 8) << 16) | ((unsigned)(h - 1) << 8);  // identity
    }
}

__global__ __launch_bounds__(256) void glass_apply(const float* __restrict__ img,
                                                   const unsigned short* __restrict__ table,
                                                   float* __restrict__ out) {
    int p = blockIdx.x * 256 + threadIdx.x;
    if (p >= IMH * IMW) return;
    int r = p / IMW;
    int c = p - r * IMW;
    int qr = r, qc = c;
    if (r >= 1) {
        int h = (r < 2) ? 2 : r;               // first segment whose domain {h-1,h} holds r
        while (h <= 223) {
            unsigned int v = table[(h - 2) * TAB_ROW_STRIDE + qc * 2 + (qr - (h - 1))];
            qr = (int)(v >> 8);
            qc = (int)(v & 255u);
            if (qr != h) break;                // landed in row h-1 -> frozen afterwards
            ++h;
        }
    }
    int q = qr * IMW + qc;
    float a0 = img[3 * q + 0];
    float a1 = img[3 * q + 1];
    float a2 = img[3 * q + 2];
    out[3 * p + 0] = fminf(fmaxf(a0, 0.0f), 1.0f);
    out[3 * p + 1] = fminf(fmaxf(a1, 0.0f), 1.0f);
    out[3 * p + 2] = fminf(fmaxf(a2, 0.0f), 1.0f);
}

extern "C" void kernel_launch(void* const* d_in, const int* in_sizes, int n_in,
                              void* d_out, int out_size, void* d_ws, size_t ws_size,
                              hipStream_t stream) {
    const float* img = (const float*)d_in[0];
    const int2* dxy = (const int2*)d_in[1];
    float* out = (float*)d_out;
    unsigned short* table = (unsigned short*)d_ws;   // 222*224*2*2 = 198,912 B

    hipLaunchKernelGGL(glass_build, dim3(NROW), dim3(64), 0, stream, dxy, table);
    hipLaunchKernelGGL(glass_apply, dim3((IMH * IMW + 255) / 256), dim3(256), 0, stream,
                       img, table, out);
}